// Round 1
// baseline (360.792 us; speedup 1.0000x reference)
//
#include <hip/hip_runtime.h>
#include <stdint.h>

typedef unsigned short u16;
typedef __bf16 bfx8 __attribute__((ext_vector_type(8)));
typedef short  sx4  __attribute__((ext_vector_type(4)));
typedef float  fx4  __attribute__((ext_vector_type(4)));
typedef u16    ux8  __attribute__((ext_vector_type(8)));
typedef u16    ux4  __attribute__((ext_vector_type(4)));
typedef float  flt4 __attribute__((ext_vector_type(4)));

#define DIM   1536
#define NH    12
#define HD    128
#define BATCH 2
#define SEQ   2048
#define MTOK  (BATCH*SEQ)
#define EPSV  1e-6f
#define SCALE 0.08838834764831845f
#define NX    (MTOK*DIM)
#define NW    (DIM*DIM)

__device__ __forceinline__ u16 f2bf(float x){
  union { float f; uint32_t u; } v; v.f = x;
  return (u16)((v.u + 0x7FFFu + ((v.u >> 16) & 1u)) >> 16);
}
__device__ __forceinline__ float bf2f(u16 h){
  union { uint32_t u; float f; } v; v.u = ((uint32_t)h) << 16; return v.f;
}
__device__ __forceinline__ void gl_lds16(const void* g, void* l){
  __builtin_amdgcn_global_load_lds((const __attribute__((address_space(1))) void*)g,
                                   (__attribute__((address_space(3))) void*)l, 16, 0, 0);
}
__device__ __forceinline__ fx4 fzero(){ fx4 z = {0.f,0.f,0.f,0.f}; return z; }

// ---------------- convert fp32 -> bf16 (x + 4 weights) ----------------
__global__ __launch_bounds__(256)
void convert_k(const float* __restrict__ x, const float* __restrict__ wq,
               const float* __restrict__ wk, const float* __restrict__ wv,
               const float* __restrict__ wo,
               u16* __restrict__ xb, u16* __restrict__ wqb, u16* __restrict__ wkb,
               u16* __restrict__ wvb, u16* __restrict__ wob)
{
  const long i4 = (long)(blockIdx.x * 256 + threadIdx.x) * 4;
  const float* src; u16* dst; long off;
  if (i4 < NX){ src = x; dst = xb; off = i4; }
  else {
    long j = i4 - NX;
    if      (j < (long)NW)   { src = wq; dst = wqb; off = j; }
    else if (j < 2L*NW)      { src = wk; dst = wkb; off = j - NW; }
    else if (j < 3L*NW)      { src = wv; dst = wvb; off = j - 2L*NW; }
    else                     { src = wo; dst = wob; off = j - 3L*NW; }
  }
  flt4 v = *(const flt4*)(src + off);
  ux4 o;
  o[0] = f2bf(v[0]); o[1] = f2bf(v[1]); o[2] = f2bf(v[2]); o[3] = f2bf(v[3]);
  *(ux4*)(dst + off) = o;
}

// ---------------- GEMM core: C = A * W^T + bias (both K-contiguous) ----------------
#define BM 128
#define BN 128
#define BK 64

// MODE 0: bf16 out + row sumsq atomics; MODE 1: bf16 out; MODE 2: f32 out
template<int MODE>
__device__ __forceinline__ void gemm_core(u16* sA, u16* sB,
                                          const u16* __restrict__ A, const u16* __restrict__ W,
                                          const float* __restrict__ bias,
                                          u16* __restrict__ outb, float* __restrict__ outf,
                                          float* __restrict__ sumsq)
{
  const int t = threadIdx.x;
  const int lane = t & 63;
  const int wid = t >> 6;
  const int wm = wid >> 1, wn = wid & 1;
  const int quad = lane >> 4, l15 = lane & 15;
  const int m0 = blockIdx.y * BM;
  const int n0 = blockIdx.x * BN;

  fx4 acc[4][4];
  #pragma unroll
  for (int i = 0; i < 4; ++i)
    #pragma unroll
    for (int j = 0; j < 4; ++j) acc[i][j] = fzero();

  const int ri  = t >> 3;   // 0..31
  const int sg0 = t & 7;

  for (int kb = 0; kb < DIM/BK; ++kb){
    const int k0 = kb * BK;
    #pragma unroll
    for (int s = 0; s < 4; ++s){
      const int row = s*32 + ri;
      const int sa = sg0 ^ (row & 7);
      gl_lds16(A + (m0+row)*DIM + k0 + sa*8, (char*)sA + s*4096 + t*16);
      gl_lds16(W + (n0+row)*DIM + k0 + sa*8, (char*)sB + s*4096 + t*16);
    }
    __syncthreads();
    #pragma unroll
    for (int kk = 0; kk < 2; ++kk){
      bfx8 af[4], bw[4];
      #pragma unroll
      for (int i = 0; i < 4; ++i){
        const int rA = wm*64 + i*16 + l15;
        af[i] = *(const bfx8*)((const char*)sA + rA*128 + (((kk*4 + quad) ^ (rA & 7)) * 16));
        const int rB = wn*64 + i*16 + l15;
        bw[i] = *(const bfx8*)((const char*)sB + rB*128 + (((kk*4 + quad) ^ (rB & 7)) * 16));
      }
      #pragma unroll
      for (int i = 0; i < 4; ++i)
        #pragma unroll
        for (int j = 0; j < 4; ++j)
          acc[i][j] = __builtin_amdgcn_mfma_f32_16x16x32_bf16(af[i], bw[j], acc[i][j], 0, 0, 0);
    }
    __syncthreads();
  }

  float bvals[4];
  #pragma unroll
  for (int j = 0; j < 4; ++j) bvals[j] = bias[n0 + wn*64 + j*16 + l15];

  #pragma unroll
  for (int i = 0; i < 4; ++i){
    #pragma unroll
    for (int r = 0; r < 4; ++r){
      const int grow = m0 + wm*64 + i*16 + quad*4 + r;
      float s2 = 0.f;
      #pragma unroll
      for (int j = 0; j < 4; ++j){
        const int gcol = n0 + wn*64 + j*16 + l15;
        const float v = acc[i][j][r] + bvals[j];
        if (MODE == 2) outf[grow*DIM + gcol] = v;
        else           outb[grow*DIM + gcol] = f2bf(v);
        s2 += v*v;
      }
      if (MODE == 0){
        s2 += __shfl_xor(s2, 1);
        s2 += __shfl_xor(s2, 2);
        s2 += __shfl_xor(s2, 4);
        s2 += __shfl_xor(s2, 8);
        if (l15 == 0) atomicAdd(&sumsq[grow], s2);
      }
    }
  }
}

__global__ __launch_bounds__(256)
void gemm_qkv_k(const u16* __restrict__ xb,
                const u16* __restrict__ wqb, const u16* __restrict__ wkb, const u16* __restrict__ wvb,
                const float* __restrict__ bq, const float* __restrict__ bk, const float* __restrict__ bv,
                u16* __restrict__ qraw, u16* __restrict__ kraw, u16* __restrict__ vraw,
                float* __restrict__ ssq, float* __restrict__ ssk)
{
  __shared__ u16 sA[BM*BK];
  __shared__ u16 sB[BN*BK];
  const int z = blockIdx.z;
  if (z == 0)      gemm_core<0>(sA, sB, xb, wqb, bq, qraw, nullptr, ssq);
  else if (z == 1) gemm_core<0>(sA, sB, xb, wkb, bk, kraw, nullptr, ssk);
  else             gemm_core<1>(sA, sB, xb, wvb, bv, vraw, nullptr, nullptr);
}

__global__ __launch_bounds__(256)
void gemm_out_k(const u16* __restrict__ attnb, const u16* __restrict__ wob,
                const float* __restrict__ bo, float* __restrict__ out)
{
  __shared__ u16 sA[BM*BK];
  __shared__ u16 sB[BN*BK];
  gemm_core<2>(sA, sB, attnb, wob, bo, nullptr, out, nullptr);
}

// ---------------- RMSNorm + RoPE (q and k) ----------------
__global__ __launch_bounds__(256)
void normrope_k(const u16* __restrict__ qraw, const u16* __restrict__ kraw,
                const float* __restrict__ ssq, const float* __restrict__ ssk,
                const float* __restrict__ gq, const float* __restrict__ gk,
                const float* __restrict__ freqs,
                u16* __restrict__ qbf, u16* __restrict__ kbf)
{
  const int row = blockIdx.x;
  const int isK = blockIdx.y;
  const u16* src   = isK ? kraw : qraw;
  const float* ss  = isK ? ssk  : ssq;
  const float* g   = isK ? gk   : gq;
  u16* dst         = isK ? kbf  : qbf;
  const int spos = row & (SEQ - 1);
  const float rstd = rsqrtf(ss[row] * (1.0f/DIM) + EPSV);
  #pragma unroll
  for (int it = 0; it < 3; ++it){
    const int p = threadIdx.x + it*256;
    const int d = p*2;
    const int hd = d & (HD-1);
    const uint32_t two = *(const uint32_t*)(src + row*DIM + d);
    const float y0 = bf2f((u16)(two & 0xFFFFu)) * rstd * g[d];
    const float y1 = bf2f((u16)(two >> 16))     * rstd * g[d+1];
    const float c  = freqs[spos*(2*HD) + hd];
    const float sn = freqs[spos*(2*HD) + HD + hd];
    const float o0 = y0*c - y1*sn;
    const float o1 = y1*c + y0*sn;
    *(uint32_t*)(dst + row*DIM + d) = (uint32_t)f2bf(o0) | ((uint32_t)f2bf(o1) << 16);
  }
}

// ---------------- V transpose: [b,tok,h,d] -> [b,h,d,tok] ----------------
__global__ __launch_bounds__(256)
void transpose_v_k(const u16* __restrict__ v, u16* __restrict__ vt)
{
  __shared__ u16 tile[64][65];
  const int t  = threadIdx.x;
  const int b  = blockIdx.z;
  const int t0 = blockIdx.x * 64;   // token tile within batch
  const int g0 = blockIdx.y * 64;   // dim-global tile (never crosses a head)
  const int r8 = t >> 3;
  const int c8 = (t & 7) * 8;
  #pragma unroll
  for (int i = 0; i < 2; ++i){
    const int row = i*32 + r8;
    ux8 val = *(const ux8*)(v + (b*SEQ + t0 + row)*DIM + g0 + c8);
    #pragma unroll
    for (int j = 0; j < 8; ++j) tile[c8 + j][row] = val[j];
  }
  __syncthreads();
  #pragma unroll
  for (int i = 0; i < 2; ++i){
    const int drow = i*32 + r8;
    const int dg = g0 + drow;
    const int h = dg >> 7, dd = dg & (HD-1);
    ux8 o;
    #pragma unroll
    for (int j = 0; j < 8; ++j) o[j] = tile[drow][c8 + j];
    *(ux8*)(vt + ((b*NH + h)*HD + dd)*SEQ + t0 + c8) = o;
  }
}

// ---------------- Flash attention ----------------
// block: 256 thr (4 waves), 64 queries x 1 head. S^T = K*Q^T via 16x16x32;
// P^T lives in S^T's C-layout == B-operand layout of 16x16x16bf16_1k -> PV with no LDS round-trip.
__global__ __launch_bounds__(256)
void flash_k(const u16* __restrict__ qbf, const u16* __restrict__ kbf, const u16* __restrict__ vt,
             const int* __restrict__ seq_lens, u16* __restrict__ attnb)
{
  __shared__ char smem[49152];   // Qs 16K | Ks 16K | Vs 16K ; epilogue reuses [0,17408)
  const int t = threadIdx.x;
  const int lane = t & 63, w = t >> 6;
  const int quad = lane >> 4, l15 = lane & 15;
  const int qt = blockIdx.x, h = blockIdx.y, b = blockIdx.z;
  const int q0 = qt * 64;
  const int tokbase = b * SEQ;
  const int kvlen = min(seq_lens[b], SEQ);
  const int ntiles = (kvlen + 63) >> 6;

  { // stage Q (once): 64 rows x 256B, 16B-chunk XOR swizzle
    const int ri = t >> 4, seg = t & 15;
    #pragma unroll
    for (int s = 0; s < 4; ++s){
      const int row = s*16 + ri;
      const int sg = seg ^ (row & 15);
      gl_lds16(qbf + (tokbase + q0 + row)*DIM + h*HD + sg*8, smem + s*4096 + t*16);
    }
  }

  fx4 o[8];
  #pragma unroll
  for (int i = 0; i < 8; ++i) o[i] = fzero();
  float mrow = -1e30f, lrow = 0.f;

  for (int kt = 0; kt < ntiles; ++kt){
    { // stage K tile
      const int ri = t >> 4, seg = t & 15;
      #pragma unroll
      for (int s = 0; s < 4; ++s){
        const int row = s*16 + ri;
        const int sg = seg ^ (row & 15);
        gl_lds16(kbf + (tokbase + kt*64 + row)*DIM + h*HD + sg*8, smem + 16384 + s*4096 + t*16);
      }
    }
    { // stage V^T tile: 128 dim-rows x 128B
      const int ri = t >> 3, seg = t & 7;
      #pragma unroll
      for (int s = 0; s < 4; ++s){
        const int row = s*32 + ri;
        const int sg = seg ^ (row & 7);
        gl_lds16(vt + ((b*NH + h)*HD + row)*SEQ + kt*64 + sg*8, smem + 32768 + s*4096 + t*16);
      }
    }
    __syncthreads();

    // S^T tiles (key x query), A=K B=Q
    fx4 st[4];
    #pragma unroll
    for (int i = 0; i < 4; ++i) st[i] = fzero();
    #pragma unroll
    for (int kk = 0; kk < 4; ++kk){
      const int qrow = w*16 + l15;
      const bfx8 qf = *(const bfx8*)(smem + qrow*256 + (((kk*4 + quad) ^ (qrow & 15)) * 16));
      #pragma unroll
      for (int i = 0; i < 4; ++i){
        const int krow = i*16 + l15;
        const bfx8 kf = *(const bfx8*)(smem + 16384 + krow*256 + (((kk*4 + quad) ^ (krow & 15)) * 16));
        st[i] = __builtin_amdgcn_mfma_f32_16x16x32_bf16(kf, qf, st[i], 0, 0, 0);
      }
    }

    // online softmax; lane owns a single query column (l15) of wave w
    float sc[4][4];
    float tm = -1e30f;
    #pragma unroll
    for (int i = 0; i < 4; ++i){
      #pragma unroll
      for (int r = 0; r < 4; ++r){
        float vv = st[i][r] * SCALE;
        const int key = kt*64 + i*16 + quad*4 + r;
        if (key >= kvlen) vv = -1e30f;
        sc[i][r] = vv;
        tm = fmaxf(tm, vv);
      }
    }
    tm = fmaxf(tm, __shfl_xor(tm, 16));
    tm = fmaxf(tm, __shfl_xor(tm, 32));
    const float mnew  = fmaxf(mrow, tm);
    const float alpha = __expf(mrow - mnew);
    float ps = 0.f;
    sx4 pb[4];
    #pragma unroll
    for (int i = 0; i < 4; ++i){
      #pragma unroll
      for (int r = 0; r < 4; ++r){
        const float p = __expf(sc[i][r] - mnew);
        ps += p;
        pb[i][r] = (short)f2bf(p);
      }
    }
    ps += __shfl_xor(ps, 16);
    ps += __shfl_xor(ps, 32);
    lrow = lrow * alpha + ps;
    mrow = mnew;
    #pragma unroll
    for (int i = 0; i < 8; ++i){
      o[i][0] *= alpha; o[i][1] *= alpha; o[i][2] *= alpha; o[i][3] *= alpha;
    }

    // O^T += V^T * P^T  (16x16x16bf16_1k; pb is already in B-operand layout)
    #pragma unroll
    for (int ks = 0; ks < 4; ++ks){
      #pragma unroll
      for (int dt = 0; dt < 8; ++dt){
        const int dim = dt*16 + l15;
        const int sg = (2*ks + (quad >> 1)) ^ (dim & 7);
        const sx4 vf = *(const sx4*)(smem + 32768 + dim*128 + sg*16 + (quad & 1)*8);
        o[dt] = __builtin_amdgcn_mfma_f32_16x16x16bf16_1k(vf, pb[ks], o[dt], 0, 0, 0);
      }
    }
    __syncthreads();
  }

  // epilogue: O^T regs -> LDS (transpose) -> coalesced global
  const float inv = 1.0f / lrow;
  u16* Os = (u16*)smem;               // [64 q][136 u16] rows (272B stride, 16B aligned)
  const int qrow = w*16 + l15;
  #pragma unroll
  for (int dt = 0; dt < 8; ++dt)
    #pragma unroll
    for (int r = 0; r < 4; ++r)
      Os[qrow*136 + dt*16 + quad*4 + r] = f2bf(o[dt][r] * inv);
  __syncthreads();
  {
    const int ri = t >> 4, seg = t & 15;
    #pragma unroll
    for (int s = 0; s < 4; ++s){
      const int row = s*16 + ri;
      const ux8 val = *(const ux8*)(Os + row*136 + seg*8);
      *(ux8*)(attnb + (tokbase + q0 + row)*DIM + h*HD + seg*8) = val;
    }
  }
}

// ---------------- launch ----------------
extern "C" void kernel_launch(void* const* d_in, const int* in_sizes, int n_in,
                              void* d_out, int out_size, void* d_ws, size_t ws_size,
                              hipStream_t stream)
{
  (void)in_sizes; (void)n_in; (void)out_size; (void)ws_size;
  const float* x      = (const float*)d_in[0];
  const float* wq     = (const float*)d_in[1];
  const float* bq     = (const float*)d_in[2];
  const float* wk     = (const float*)d_in[3];
  const float* bk     = (const float*)d_in[4];
  const float* wv     = (const float*)d_in[5];
  const float* bv     = (const float*)d_in[6];
  const float* wo     = (const float*)d_in[7];
  const float* bo     = (const float*)d_in[8];
  const float* gq     = (const float*)d_in[9];
  const float* gk     = (const float*)d_in[10];
  const float* freqs  = (const float*)d_in[11];
  const int*   seqls  = (const int*)d_in[12];

  char* ws = (char*)d_ws;
  u16* xb   = (u16*)(ws + 0);          // 12.6 MB; reused as vt after QKV GEMM
  u16* wqb  = (u16*)(ws + 12582912);
  u16* wkb  = (u16*)(ws + 17301504);
  u16* wvb  = (u16*)(ws + 22020096);
  u16* wob  = (u16*)(ws + 26738688);
  u16* qraw = (u16*)(ws + 31457280);   // reused as attn after normrope
  u16* kraw = (u16*)(ws + 44040192);
  u16* vraw = (u16*)(ws + 56623104);
  u16* qbf  = (u16*)(ws + 69206016);
  u16* kbf  = (u16*)(ws + 81788928);
  float* ssq = (float*)(ws + 94371840);
  float* ssk = (float*)(ws + 94388224);
  u16* vt    = xb;
  u16* attnb = qraw;

  (void)hipMemsetAsync(ssq, 0, 32768, stream);   // zero both sumsq buffers (contiguous)

  convert_k   <<<15360, 256, 0, stream>>>(x, wq, wk, wv, wo, xb, wqb, wkb, wvb, wob);
  gemm_qkv_k  <<<dim3(12, 32, 3), 256, 0, stream>>>(xb, wqb, wkb, wvb, bq, bk, bv,
                                                    qraw, kraw, vraw, ssq, ssk);
  normrope_k  <<<dim3(4096, 2), 256, 0, stream>>>(qraw, kraw, ssq, ssk, gq, gk, freqs, qbf, kbf);
  transpose_v_k<<<dim3(32, 24, 2), 256, 0, stream>>>(vraw, vt);
  flash_k     <<<dim3(32, 12, 2), 256, 0, stream>>>(qbf, kbf, vt, seqls, attnb);
  gemm_out_k  <<<dim3(12, 32), 256, 0, stream>>>(attnb, wob, bo, (float*)d_out);
}

// Round 2
// 344.563 us; speedup vs baseline: 1.0471x; 1.0471x over previous
//
#include <hip/hip_runtime.h>
#include <stdint.h>

typedef unsigned short u16;
typedef __bf16 bfx8 __attribute__((ext_vector_type(8)));
typedef short  sx4  __attribute__((ext_vector_type(4)));
typedef float  fx4  __attribute__((ext_vector_type(4)));
typedef float  fx16 __attribute__((ext_vector_type(16)));
typedef u16    ux8  __attribute__((ext_vector_type(8)));
typedef u16    ux4  __attribute__((ext_vector_type(4)));
typedef float  flt4 __attribute__((ext_vector_type(4)));

#define DIM   1536
#define NH    12
#define HD    128
#define BATCH 2
#define SEQ   2048
#define MTOK  (BATCH*SEQ)
#define EPSV  1e-6f
#define SCALE 0.08838834764831845f
#define NX    (MTOK*DIM)
#define NW    (DIM*DIM)

__device__ __forceinline__ u16 f2bf(float x){
  union { float f; uint32_t u; } v; v.f = x;
  return (u16)((v.u + 0x7FFFu + ((v.u >> 16) & 1u)) >> 16);
}
__device__ __forceinline__ float bf2f(u16 h){
  union { uint32_t u; float f; } v; v.u = ((uint32_t)h) << 16; return v.f;
}
__device__ __forceinline__ void gl_lds16(const void* g, void* l){
  __builtin_amdgcn_global_load_lds((const __attribute__((address_space(1))) void*)g,
                                   (__attribute__((address_space(3))) void*)l, 16, 0, 0);
}
__device__ __forceinline__ fx4 fzero(){ fx4 z = {0.f,0.f,0.f,0.f}; return z; }

// ---------------- convert fp32 -> bf16 (x + 4 weights) ----------------
__global__ __launch_bounds__(256)
void convert_k(const float* __restrict__ x, const float* __restrict__ wq,
               const float* __restrict__ wk, const float* __restrict__ wv,
               const float* __restrict__ wo,
               u16* __restrict__ xb, u16* __restrict__ wqb, u16* __restrict__ wkb,
               u16* __restrict__ wvb, u16* __restrict__ wob)
{
  const long i4 = (long)(blockIdx.x * 256 + threadIdx.x) * 4;
  const float* src; u16* dst; long off;
  if (i4 < NX){ src = x; dst = xb; off = i4; }
  else {
    long j = i4 - NX;
    if      (j < (long)NW)   { src = wq; dst = wqb; off = j; }
    else if (j < 2L*NW)      { src = wk; dst = wkb; off = j - NW; }
    else if (j < 3L*NW)      { src = wv; dst = wvb; off = j - 2L*NW; }
    else                     { src = wo; dst = wob; off = j - 3L*NW; }
  }
  flt4 v = *(const flt4*)(src + off);
  ux4 o;
  o[0] = f2bf(v[0]); o[1] = f2bf(v[1]); o[2] = f2bf(v[2]); o[3] = f2bf(v[3]);
  *(ux4*)(dst + off) = o;
}

// ---------------- GEMM core: C = A * W^T + bias (both K-contiguous) ----------------
#define BM 128
#define BN 128
#define BK 64

// MODE 0: bf16 out + row sumsq atomics; MODE 1: bf16 out; MODE 2: f32 out
template<int MODE>
__device__ __forceinline__ void gemm_core(u16* sA, u16* sB,
                                          const u16* __restrict__ A, const u16* __restrict__ W,
                                          const float* __restrict__ bias,
                                          u16* __restrict__ outb, float* __restrict__ outf,
                                          float* __restrict__ sumsq)
{
  const int t = threadIdx.x;
  const int lane = t & 63;
  const int wid = t >> 6;
  const int wm = wid >> 1, wn = wid & 1;
  const int quad = lane >> 4, l15 = lane & 15;
  const int m0 = blockIdx.y * BM;
  const int n0 = blockIdx.x * BN;

  fx4 acc[4][4];
  #pragma unroll
  for (int i = 0; i < 4; ++i)
    #pragma unroll
    for (int j = 0; j < 4; ++j) acc[i][j] = fzero();

  const int ri  = t >> 3;   // 0..31
  const int sg0 = t & 7;

  for (int kb = 0; kb < DIM/BK; ++kb){
    const int k0 = kb * BK;
    #pragma unroll
    for (int s = 0; s < 4; ++s){
      const int row = s*32 + ri;
      const int sa = sg0 ^ (row & 7);
      gl_lds16(A + (m0+row)*DIM + k0 + sa*8, (char*)sA + s*4096 + t*16);
      gl_lds16(W + (n0+row)*DIM + k0 + sa*8, (char*)sB + s*4096 + t*16);
    }
    __syncthreads();
    #pragma unroll
    for (int kk = 0; kk < 2; ++kk){
      bfx8 af[4], bw[4];
      #pragma unroll
      for (int i = 0; i < 4; ++i){
        const int rA = wm*64 + i*16 + l15;
        af[i] = *(const bfx8*)((const char*)sA + rA*128 + (((kk*4 + quad) ^ (rA & 7)) * 16));
        const int rB = wn*64 + i*16 + l15;
        bw[i] = *(const bfx8*)((const char*)sB + rB*128 + (((kk*4 + quad) ^ (rB & 7)) * 16));
      }
      #pragma unroll
      for (int i = 0; i < 4; ++i)
        #pragma unroll
        for (int j = 0; j < 4; ++j)
          acc[i][j] = __builtin_amdgcn_mfma_f32_16x16x32_bf16(af[i], bw[j], acc[i][j], 0, 0, 0);
    }
    __syncthreads();
  }

  float bvals[4];
  #pragma unroll
  for (int j = 0; j < 4; ++j) bvals[j] = bias[n0 + wn*64 + j*16 + l15];

  #pragma unroll
  for (int i = 0; i < 4; ++i){
    #pragma unroll
    for (int r = 0; r < 4; ++r){
      const int grow = m0 + wm*64 + i*16 + quad*4 + r;
      float s2 = 0.f;
      #pragma unroll
      for (int j = 0; j < 4; ++j){
        const int gcol = n0 + wn*64 + j*16 + l15;
        const float v = acc[i][j][r] + bvals[j];
        if (MODE == 2) outf[grow*DIM + gcol] = v;
        else           outb[grow*DIM + gcol] = f2bf(v);
        s2 += v*v;
      }
      if (MODE == 0){
        s2 += __shfl_xor(s2, 1);
        s2 += __shfl_xor(s2, 2);
        s2 += __shfl_xor(s2, 4);
        s2 += __shfl_xor(s2, 8);
        if (l15 == 0) atomicAdd(&sumsq[grow], s2);
      }
    }
  }
}

__global__ __launch_bounds__(256)
void gemm_qkv_k(const u16* __restrict__ xb,
                const u16* __restrict__ wqb, const u16* __restrict__ wkb, const u16* __restrict__ wvb,
                const float* __restrict__ bq, const float* __restrict__ bk, const float* __restrict__ bv,
                u16* __restrict__ qraw, u16* __restrict__ kraw, u16* __restrict__ vraw,
                float* __restrict__ ssq, float* __restrict__ ssk)
{
  __shared__ u16 sA[BM*BK];
  __shared__ u16 sB[BN*BK];
  const int z = blockIdx.z;
  if (z == 0)      gemm_core<0>(sA, sB, xb, wqb, bq, qraw, nullptr, ssq);
  else if (z == 1) gemm_core<0>(sA, sB, xb, wkb, bk, kraw, nullptr, ssk);
  else             gemm_core<1>(sA, sB, xb, wvb, bv, vraw, nullptr, nullptr);
}

__global__ __launch_bounds__(256)
void gemm_out_k(const u16* __restrict__ attnb, const u16* __restrict__ wob,
                const float* __restrict__ bo, float* __restrict__ out)
{
  __shared__ u16 sA[BM*BK];
  __shared__ u16 sB[BN*BK];
  gemm_core<2>(sA, sB, attnb, wob, bo, nullptr, out, nullptr);
}

// ---------------- RMSNorm + RoPE (q and k); Q additionally pre-scaled by 1/sqrt(d) ----------------
__global__ __launch_bounds__(256)
void normrope_k(const u16* __restrict__ qraw, const u16* __restrict__ kraw,
                const float* __restrict__ ssq, const float* __restrict__ ssk,
                const float* __restrict__ gq, const float* __restrict__ gk,
                const float* __restrict__ freqs,
                u16* __restrict__ qbf, u16* __restrict__ kbf)
{
  const int row = blockIdx.x;
  const int isK = blockIdx.y;
  const u16* src   = isK ? kraw : qraw;
  const float* ss  = isK ? ssk  : ssq;
  const float* g   = isK ? gk   : gq;
  u16* dst         = isK ? kbf  : qbf;
  const int spos = row & (SEQ - 1);
  float rstd = rsqrtf(ss[row] * (1.0f/DIM) + EPSV);
  if (!isK) rstd *= SCALE;   // fold softmax scale into Q
  #pragma unroll
  for (int it = 0; it < 3; ++it){
    const int p = threadIdx.x + it*256;
    const int d = p*2;
    const int hd = d & (HD-1);
    const uint32_t two = *(const uint32_t*)(src + row*DIM + d);
    const float y0 = bf2f((u16)(two & 0xFFFFu)) * rstd * g[d];
    const float y1 = bf2f((u16)(two >> 16))     * rstd * g[d+1];
    const float c  = freqs[spos*(2*HD) + hd];
    const float sn = freqs[spos*(2*HD) + HD + hd];
    const float o0 = y0*c - y1*sn;
    const float o1 = y1*c + y0*sn;
    *(uint32_t*)(dst + row*DIM + d) = (uint32_t)f2bf(o0) | ((uint32_t)f2bf(o1) << 16);
  }
}

// ---------------- V transpose: [b,tok,h,d] -> [b,h,d,tok] ----------------
__global__ __launch_bounds__(256)
void transpose_v_k(const u16* __restrict__ v, u16* __restrict__ vt)
{
  __shared__ u16 tile[64][65];
  const int t  = threadIdx.x;
  const int b  = blockIdx.z;
  const int t0 = blockIdx.x * 64;   // token tile within batch
  const int g0 = blockIdx.y * 64;   // dim-global tile (never crosses a head)
  const int r8 = t >> 3;
  const int c8 = (t & 7) * 8;
  #pragma unroll
  for (int i = 0; i < 2; ++i){
    const int row = i*32 + r8;
    ux8 val = *(const ux8*)(v + (b*SEQ + t0 + row)*DIM + g0 + c8);
    #pragma unroll
    for (int j = 0; j < 8; ++j) tile[c8 + j][row] = val[j];
  }
  __syncthreads();
  #pragma unroll
  for (int i = 0; i < 2; ++i){
    const int drow = i*32 + r8;
    const int dg = g0 + drow;
    const int h = dg >> 7, dd = dg & (HD-1);
    ux8 o;
    #pragma unroll
    for (int j = 0; j < 8; ++j) o[j] = tile[drow][c8 + j];
    *(ux8*)(vt + ((b*NH + h)*HD + dd)*SEQ + t0 + c8) = o;
  }
}

// ---------------- Flash attention (32x32 MFMA, 2q-wave x 2k-wave split) ----------------
// Block: 256 thr. wq = (t>>6)&1 owns 32 queries; wk = t>>7 owns a 32-key half of each 64-key tile.
// S^T = K * Q^T via mfma_32x32x16_bf16 (A=K frag b128 from LDS, B=Q frag in regs).
// S^T C-regs [4ks..4ks+3] ARE the B-operand of mfma_32x32x8bf16_1k -> PV with zero shuffles.
// Each (wk,wq) wave keeps independent online-softmax state; merged once in epilogue.
__global__ __launch_bounds__(256, 3)
void flash_k(const u16* __restrict__ qbf, const u16* __restrict__ kbf, const u16* __restrict__ vt,
             const int* __restrict__ seq_lens, u16* __restrict__ attnb)
{
  __shared__ char smem[49152];  // [0,16K) K | [16K,32K) V^T ; epi: [0,32K) O1-exchange, [32K,48K) ml+Os
  const int t = threadIdx.x;
  const int lane = t & 63;
  const int h = lane >> 5;          // half-wave
  const int l31 = lane & 31;
  const int wq = (t >> 6) & 1;
  const int wk = t >> 7;
  const int hh = blockIdx.y, b = blockIdx.z;
  const int q0 = blockIdx.x * 64 + wq * 32;
  const int tokbase = b * SEQ;
  const int kvlen = min(seq_lens[b], SEQ);
  const int ntiles = (kvlen + 63) >> 6;

  // Q fragments in registers (B-operand layout: n=l31 -> query, k=h*8+j -> d)
  bfx8 qf[8];
  {
    const u16* qp = qbf + (size_t)(tokbase + q0 + l31)*DIM + hh*HD + h*8;
    #pragma unroll
    for (int c = 0; c < 8; ++c) qf[c] = *(const bfx8*)(qp + c*16);
  }

  fx16 o[4];
  #pragma unroll
  for (int dt = 0; dt < 4; ++dt)
    #pragma unroll
    for (int r = 0; r < 16; ++r) o[dt][r] = 0.f;
  float mrow = -1e30f, lrow = 0.f;

  // staging index precompute
  const int kri = t >> 4, kseg = t & 15;       // K: 16 rows x 16 chunks per pass
  const int vri = t >> 3, vseg = t & 7;        // V: 32 rows x 8 chunks per pass
  const int krow = wk*32 + l31;                // K-frag LDS row (const)

  for (int kt = 0; kt < ntiles; ++kt){
    { // stage K tile: 64 rows x 256B
      #pragma unroll
      for (int s = 0; s < 4; ++s){
        const int row = s*16 + kri;
        const int sg = kseg ^ (row & 15);
        gl_lds16(kbf + (size_t)(tokbase + kt*64 + row)*DIM + hh*HD + sg*8, smem + s*4096 + t*16);
      }
    }
    { // stage V^T tile: 128 d-rows x 128B
      #pragma unroll
      for (int s = 0; s < 4; ++s){
        const int row = s*32 + vri;
        const int sg = vseg ^ (row & 7);
        gl_lds16(vt + (size_t)((b*NH + hh)*HD + row)*SEQ + kt*64 + sg*8, smem + 16384 + s*4096 + t*16);
      }
    }
    __syncthreads();

    // S^T (32k x 32q) for this wave's key half
    fx16 st;
    #pragma unroll
    for (int r = 0; r < 16; ++r) st[r] = 0.f;
    #pragma unroll
    for (int c = 0; c < 8; ++c){
      const bfx8 kf = *(const bfx8*)(smem + krow*256 + (((2*c + h) ^ (krow & 15)) << 4));
      st = __builtin_amdgcn_mfma_f32_32x32x16_bf16(kf, qf[c], st, 0, 0, 0);
    }

    // tail masking (never taken for seq_lens multiple of 64; kept for generality)
    if ((kt == ntiles - 1) && (kvlen & 63)){
      #pragma unroll
      for (int r = 0; r < 16; ++r){
        const int key = kt*64 + wk*32 + (r & 3) + 8*(r >> 2) + 4*h;
        if (key >= kvlen) st[r] = -1e30f;
      }
    }

    // online softmax (lane owns query col l31; keys split across h halves)
    float tm = st[0];
    #pragma unroll
    for (int r = 1; r < 16; ++r) tm = fmaxf(tm, st[r]);
    tm = fmaxf(tm, __shfl_xor(tm, 32));
    if (__any(tm > mrow)){
      const float mnew = fmaxf(mrow, tm);
      const float alpha = __expf(mrow - mnew);
      lrow *= alpha;
      #pragma unroll
      for (int dt = 0; dt < 4; ++dt)
        #pragma unroll
        for (int r = 0; r < 16; ++r) o[dt][r] *= alpha;
      mrow = mnew;
    }

    // p = exp(s - m), round-half-up to bf16 via +0x8000, Sigma-p from the ROUNDED values
    uint32_t tt[16];
    float ps = 0.f;
    #pragma unroll
    for (int r = 0; r < 16; ++r){
      union { float f; uint32_t u; } e; e.f = __expf(st[r] - mrow);
      const uint32_t u = e.u + 0x8000u;
      tt[r] = u;
      union { uint32_t u; float f; } pm; pm.u = u & 0xFFFF0000u;
      ps += pm.f;
    }
    ps += __shfl_xor(ps, 32);
    lrow += ps;

    sx4 pb[4];
    #pragma unroll
    for (int ks = 0; ks < 4; ++ks){
      union { uint32_t u[2]; sx4 s; } pk;
      pk.u[0] = __builtin_amdgcn_perm(tt[4*ks+1], tt[4*ks+0], 0x07060302u);
      pk.u[1] = __builtin_amdgcn_perm(tt[4*ks+3], tt[4*ks+2], 0x07060302u);
      pb[ks] = pk.s;
    }

    // O^T += V^T * P^T   (A = V^T frag b64 from LDS, B = P^T = S C-regs directly)
    #pragma unroll
    for (int ks = 0; ks < 4; ++ks){
      #pragma unroll
      for (int dt = 0; dt < 4; ++dt){
        const int row = dt*32 + l31;
        const sx4 vf = *(const sx4*)(smem + 16384 + row*128 + ((((wk<<2) + ks) ^ (row & 7)) << 4) + (h << 3));
        o[dt] = __builtin_amdgcn_mfma_f32_32x32x8bf16_1k(vf, pb[ks], o[dt], 0, 0, 0);
      }
    }
    __syncthreads();
  }

  // ---- epilogue: merge wk halves, normalize, store ----
  float* mlbuf = (float*)(smem + 32768);     // [wk][wq][2][32]
  if (h == 0){
    mlbuf[((wk*2 + wq)*2 + 0)*32 + l31] = mrow;
    mlbuf[((wk*2 + wq)*2 + 1)*32 + l31] = lrow;
  }
  __syncthreads();
  const float mo = mlbuf[(((wk^1)*2 + wq)*2 + 0)*32 + l31];
  const float lo = mlbuf[(((wk^1)*2 + wq)*2 + 1)*32 + l31];
  const float M  = fmaxf(mrow, mo);
  const float f  = __expf(mrow - M);
  const float L  = lrow * f + lo * __expf(mo - M);
  #pragma unroll
  for (int dt = 0; dt < 4; ++dt)
    #pragma unroll
    for (int r = 0; r < 16; ++r) o[dt][r] *= f;
  __syncthreads();                            // mlbuf consumed by all

  float* xbuf = (float*)smem;                 // [wq][32 q][128 d] fp32 (wk=1's scaled O)
  if (wk == 1){
    #pragma unroll
    for (int dt = 0; dt < 4; ++dt)
      #pragma unroll
      for (int rq = 0; rq < 4; ++rq){
        const int d = dt*32 + 8*rq + 4*h;
        fx4 v4; v4[0]=o[dt][4*rq]; v4[1]=o[dt][4*rq+1]; v4[2]=o[dt][4*rq+2]; v4[3]=o[dt][4*rq+3];
        *(fx4*)(xbuf + (size_t)(wq*32 + l31)*128 + d) = v4;
      }
  }
  __syncthreads();

  u16* Os = (u16*)(smem + 32768);             // [64 q][128 d] bf16
  if (wk == 0){
    const float invL = 1.0f / L;
    #pragma unroll
    for (int dt = 0; dt < 4; ++dt)
      #pragma unroll
      for (int rq = 0; rq < 4; ++rq){
        const int d = dt*32 + 8*rq + 4*h;
        const fx4 p4 = *(const fx4*)(xbuf + (size_t)(wq*32 + l31)*128 + d);
        ux4 b4;
        #pragma unroll
        for (int j = 0; j < 4; ++j) b4[j] = f2bf((o[dt][4*rq + j] + p4[j]) * invL);
        *(ux4*)(Os + (size_t)(wq*32 + l31)*128 + d) = b4;
      }
  }
  __syncthreads();
  {
    const int ri = t >> 4, seg = t & 15;
    #pragma unroll
    for (int s = 0; s < 4; ++s){
      const int row = s*16 + ri;
      const ux8 val = *(const ux8*)(Os + row*128 + seg*8);
      *(ux8*)(attnb + (size_t)(tokbase + blockIdx.x*64 + row)*DIM + hh*HD + seg*8) = val;
    }
  }
}

// ---------------- launch ----------------
extern "C" void kernel_launch(void* const* d_in, const int* in_sizes, int n_in,
                              void* d_out, int out_size, void* d_ws, size_t ws_size,
                              hipStream_t stream)
{
  (void)in_sizes; (void)n_in; (void)out_size; (void)ws_size;
  const float* x      = (const float*)d_in[0];
  const float* wq     = (const float*)d_in[1];
  const float* bq     = (const float*)d_in[2];
  const float* wk     = (const float*)d_in[3];
  const float* bk     = (const float*)d_in[4];
  const float* wv     = (const float*)d_in[5];
  const float* bv     = (const float*)d_in[6];
  const float* wo     = (const float*)d_in[7];
  const float* bo     = (const float*)d_in[8];
  const float* gq     = (const float*)d_in[9];
  const float* gk     = (const float*)d_in[10];
  const float* freqs  = (const float*)d_in[11];
  const int*   seqls  = (const int*)d_in[12];

  char* ws = (char*)d_ws;
  u16* xb   = (u16*)(ws + 0);          // 12.6 MB; reused as vt after QKV GEMM
  u16* wqb  = (u16*)(ws + 12582912);
  u16* wkb  = (u16*)(ws + 17301504);
  u16* wvb  = (u16*)(ws + 22020096);
  u16* wob  = (u16*)(ws + 26738688);
  u16* qraw = (u16*)(ws + 31457280);   // reused as attn after normrope
  u16* kraw = (u16*)(ws + 44040192);
  u16* vraw = (u16*)(ws + 56623104);
  u16* qbf  = (u16*)(ws + 69206016);
  u16* kbf  = (u16*)(ws + 81788928);
  float* ssq = (float*)(ws + 94371840);
  float* ssk = (float*)(ws + 94388224);
  u16* vt    = xb;
  u16* attnb = qraw;

  (void)hipMemsetAsync(ssq, 0, 32768, stream);   // zero both sumsq buffers (contiguous)

  convert_k   <<<15360, 256, 0, stream>>>(x, wq, wk, wv, wo, xb, wqb, wkb, wvb, wob);
  gemm_qkv_k  <<<dim3(12, 32, 3), 256, 0, stream>>>(xb, wqb, wkb, wvb, bq, bk, bv,
                                                    qraw, kraw, vraw, ssq, ssk);
  normrope_k  <<<dim3(4096, 2), 256, 0, stream>>>(qraw, kraw, ssq, ssk, gq, gk, freqs, qbf, kbf);
  transpose_v_k<<<dim3(32, 24, 2), 256, 0, stream>>>(vraw, vt);
  flash_k     <<<dim3(32, 12, 2), 256, 0, stream>>>(qbf, kbf, vt, seqls, attnb);
  gemm_out_k  <<<dim3(12, 32), 256, 0, stream>>>(attnb, wob, bo, (float*)d_out);
}

// Round 3
// 316.312 us; speedup vs baseline: 1.1406x; 1.0893x over previous
//
#include <hip/hip_runtime.h>
#include <stdint.h>

typedef unsigned short u16;
typedef __bf16 bfx8 __attribute__((ext_vector_type(8)));
typedef short  sx4  __attribute__((ext_vector_type(4)));
typedef float  fx4  __attribute__((ext_vector_type(4)));
typedef float  fx16 __attribute__((ext_vector_type(16)));
typedef u16    ux8  __attribute__((ext_vector_type(8)));
typedef u16    ux4  __attribute__((ext_vector_type(4)));
typedef float  flt4 __attribute__((ext_vector_type(4)));

#define DIM   1536
#define NH    12
#define HD    128
#define BATCH 2
#define SEQ   2048
#define MTOK  (BATCH*SEQ)
#define EPSV  1e-6f
#define SCALE 0.08838834764831845f
#define NX    (MTOK*DIM)
#define NW    (DIM*DIM)

__device__ __forceinline__ u16 f2bf(float x){
  union { float f; uint32_t u; } v; v.f = x;
  return (u16)((v.u + 0x7FFFu + ((v.u >> 16) & 1u)) >> 16);
}
__device__ __forceinline__ float bf2f(u16 h){
  union { uint32_t u; float f; } v; v.u = ((uint32_t)h) << 16; return v.f;
}
__device__ __forceinline__ void gl_lds16(const void* g, void* l){
  __builtin_amdgcn_global_load_lds((const __attribute__((address_space(1))) void*)g,
                                   (__attribute__((address_space(3))) void*)l, 16, 0, 0);
}
__device__ __forceinline__ fx4 fzero(){ fx4 z = {0.f,0.f,0.f,0.f}; return z; }

// ---------------- convert fp32 -> bf16 (x + 4 weights) ----------------
__global__ __launch_bounds__(256)
void convert_k(const float* __restrict__ x, const float* __restrict__ wq,
               const float* __restrict__ wk, const float* __restrict__ wv,
               const float* __restrict__ wo,
               u16* __restrict__ xb, u16* __restrict__ wqb, u16* __restrict__ wkb,
               u16* __restrict__ wvb, u16* __restrict__ wob)
{
  const long i4 = (long)(blockIdx.x * 256 + threadIdx.x) * 4;
  const float* src; u16* dst; long off;
  if (i4 < NX){ src = x; dst = xb; off = i4; }
  else {
    long j = i4 - NX;
    if      (j < (long)NW)   { src = wq; dst = wqb; off = j; }
    else if (j < 2L*NW)      { src = wk; dst = wkb; off = j - NW; }
    else if (j < 3L*NW)      { src = wv; dst = wvb; off = j - 2L*NW; }
    else                     { src = wo; dst = wob; off = j - 3L*NW; }
  }
  flt4 v = *(const flt4*)(src + off);
  ux4 o;
  o[0] = f2bf(v[0]); o[1] = f2bf(v[1]); o[2] = f2bf(v[2]); o[3] = f2bf(v[3]);
  *(ux4*)(dst + off) = o;
}

// ---------------- GEMM core: C = A * W^T + bias, double-buffered LDS ----------------
#define BM 128
#define BN 128
#define BK 64
#define NKIT (DIM/BK)

// MODE 0: bf16 out + row sumsq atomics; MODE 1: V -> transposed vt out; MODE 2: f32 out
template<int MODE>
__device__ __forceinline__ void gemm_core(char* smem,
                                          const u16* __restrict__ A, const u16* __restrict__ W,
                                          const float* __restrict__ bias,
                                          u16* __restrict__ outb, float* __restrict__ outf,
                                          float* __restrict__ sumsq, u16* __restrict__ vtout)
{
  const int t = threadIdx.x;
  const int lane = t & 63;
  const int wid = t >> 6;
  const int wm = wid >> 1, wn = wid & 1;
  const int quad = lane >> 4, l15 = lane & 15;

  // XCD-aware swizzle: the 12 blocks sharing an A-stripe land on one XCD
  const int lin = blockIdx.y * 12 + blockIdx.x;   // dispatch-linear within z
  const int r   = lin >> 3;                        // 0..47
  const int m0  = ((lin & 7) + 8 * (r / 12)) * BM;
  const int n0  = (r % 12) * BN;

  fx4 acc[4][4];
  #pragma unroll
  for (int i = 0; i < 4; ++i)
    #pragma unroll
    for (int j = 0; j < 4; ++j) acc[i][j] = fzero();

  const int ri  = t >> 3;   // 0..31
  const int sg0 = t & 7;

  // stage K-block kb into buffer p (p*32768: A 16K | B 16K)
  auto stage = [&](int kb, int p){
    const int k0 = kb * BK;
    char* base = smem + p * 32768;
    #pragma unroll
    for (int s = 0; s < 4; ++s){
      const int row = s*32 + ri;
      const int sa = sg0 ^ (row & 7);
      gl_lds16(A + (size_t)(m0+row)*DIM + k0 + sa*8, base + s*4096 + t*16);
      gl_lds16(W + (size_t)(n0+row)*DIM + k0 + sa*8, base + 16384 + s*4096 + t*16);
    }
  };

  stage(0, 0);
  for (int kb = 0; kb < NKIT; ++kb){
    char* cur = smem + (kb & 1) * 32768;
    __syncthreads();                       // drains stage(kb); frees buf (kb+1)&1
    if (kb + 1 < NKIT) stage(kb + 1, (kb + 1) & 1);
    #pragma unroll
    for (int kk = 0; kk < 2; ++kk){
      bfx8 af[4], bw[4];
      #pragma unroll
      for (int i = 0; i < 4; ++i){
        const int rA = wm*64 + i*16 + l15;
        af[i] = *(const bfx8*)(cur + rA*128 + (((kk*4 + quad) ^ (rA & 7)) * 16));
        const int rB = wn*64 + i*16 + l15;
        bw[i] = *(const bfx8*)(cur + 16384 + rB*128 + (((kk*4 + quad) ^ (rB & 7)) * 16));
      }
      #pragma unroll
      for (int i = 0; i < 4; ++i)
        #pragma unroll
        for (int j = 0; j < 4; ++j)
          acc[i][j] = __builtin_amdgcn_mfma_f32_16x16x32_bf16(af[i], bw[j], acc[i][j], 0, 0, 0);
    }
  }

  float bvals[4];
  #pragma unroll
  for (int j = 0; j < 4; ++j) bvals[j] = bias[n0 + wn*64 + j*16 + l15];

  if (MODE == 1){
    // V epilogue: bf16 transpose via XOR-swizzled LDS tile, then coalesced vt write.
    // T layout: col*256B + ((rowchunk ^ (col&15))*16 + (row&7)*2
    u16* T = (u16*)smem;   // 32 KB at buf0 (compute(last) read buf1; buf0 is free)
    #pragma unroll
    for (int i = 0; i < 4; ++i){
      const int row0  = wm*64 + i*16 + quad*4;
      const int chunk = row0 >> 3;
      const int half  = quad & 1;
      #pragma unroll
      for (int j = 0; j < 4; ++j){
        const int col = wn*64 + j*16 + l15;
        ux4 w4;
        #pragma unroll
        for (int rr = 0; rr < 4; ++rr) w4[rr] = f2bf(acc[i][j][rr] + bvals[j]);
        *(ux4*)((char*)T + col*256 + ((chunk ^ (col & 15)) << 4) + half*8) = w4;
      }
    }
    __syncthreads();
    const int b   = m0 >> 11;       // SEQ = 2048
    const int m0l = m0 & (SEQ - 1);
    const int cr  = t & 15;         // row chunk (8 toks)
    #pragma unroll
    for (int s = 0; s < 8; ++s){
      const int cl = s*16 + (t >> 4);
      const ux8 v = *(const ux8*)((char*)T + cl*256 + ((cr ^ (cl & 15)) << 4));
      const int cg = n0 + cl;
      const int hh = cg >> 7, dd = cg & (HD - 1);
      *(ux8*)(vtout + (size_t)((b*NH + hh)*HD + dd)*SEQ + m0l + cr*8) = v;
    }
    return;
  }

  #pragma unroll
  for (int i = 0; i < 4; ++i){
    #pragma unroll
    for (int rr = 0; rr < 4; ++rr){
      const int grow = m0 + wm*64 + i*16 + quad*4 + rr;
      float s2 = 0.f;
      #pragma unroll
      for (int j = 0; j < 4; ++j){
        const int gcol = n0 + wn*64 + j*16 + l15;
        const float v = acc[i][j][rr] + bvals[j];
        if (MODE == 2) outf[(size_t)grow*DIM + gcol] = v;
        else           outb[(size_t)grow*DIM + gcol] = f2bf(v);
        s2 += v*v;
      }
      if (MODE == 0){
        s2 += __shfl_xor(s2, 1);
        s2 += __shfl_xor(s2, 2);
        s2 += __shfl_xor(s2, 4);
        s2 += __shfl_xor(s2, 8);
        if (l15 == 0) atomicAdd(&sumsq[grow], s2);
      }
    }
  }
}

__global__ __launch_bounds__(256)
void gemm_qkv_k(const u16* __restrict__ xb,
                const u16* __restrict__ wqb, const u16* __restrict__ wkb, const u16* __restrict__ wvb,
                const float* __restrict__ bq, const float* __restrict__ bk, const float* __restrict__ bv,
                u16* __restrict__ qraw, u16* __restrict__ kraw, u16* __restrict__ vt,
                float* __restrict__ ssq, float* __restrict__ ssk)
{
  __shared__ char smem[65536];
  const int z = blockIdx.z;
  if (z == 0)      gemm_core<0>(smem, xb, wqb, bq, qraw, nullptr, ssq, nullptr);
  else if (z == 1) gemm_core<0>(smem, xb, wkb, bk, kraw, nullptr, ssk, nullptr);
  else             gemm_core<1>(smem, xb, wvb, bv, nullptr, nullptr, nullptr, vt);
}

__global__ __launch_bounds__(256)
void gemm_out_k(const u16* __restrict__ attnb, const u16* __restrict__ wob,
                const float* __restrict__ bo, float* __restrict__ out)
{
  __shared__ char smem[65536];
  gemm_core<2>(smem, attnb, wob, bo, nullptr, out, nullptr, nullptr);
}

// ---------------- RMSNorm + RoPE (q and k); Q additionally pre-scaled by 1/sqrt(d) ----------------
__global__ __launch_bounds__(256)
void normrope_k(const u16* __restrict__ qraw, const u16* __restrict__ kraw,
                const float* __restrict__ ssq, const float* __restrict__ ssk,
                const float* __restrict__ gq, const float* __restrict__ gk,
                const float* __restrict__ freqs,
                u16* __restrict__ qbf, u16* __restrict__ kbf)
{
  const int row = blockIdx.x;
  const int isK = blockIdx.y;
  const u16* src   = isK ? kraw : qraw;
  const float* ss  = isK ? ssk  : ssq;
  const float* g   = isK ? gk   : gq;
  u16* dst         = isK ? kbf  : qbf;
  const int spos = row & (SEQ - 1);
  float rstd = rsqrtf(ss[row] * (1.0f/DIM) + EPSV);
  if (!isK) rstd *= SCALE;   // fold softmax scale into Q
  #pragma unroll
  for (int it = 0; it < 3; ++it){
    const int p = threadIdx.x + it*256;
    const int d = p*2;
    const int hd = d & (HD-1);
    const uint32_t two = *(const uint32_t*)(src + (size_t)row*DIM + d);
    const float y0 = bf2f((u16)(two & 0xFFFFu)) * rstd * g[d];
    const float y1 = bf2f((u16)(two >> 16))     * rstd * g[d+1];
    const float c  = freqs[spos*(2*HD) + hd];
    const float sn = freqs[spos*(2*HD) + HD + hd];
    const float o0 = y0*c - y1*sn;
    const float o1 = y1*c + y0*sn;
    *(uint32_t*)(dst + (size_t)row*DIM + d) = (uint32_t)f2bf(o0) | ((uint32_t)f2bf(o1) << 16);
  }
}

// ---------------- Flash attention (32x32 MFMA, 2q-wave x 2k-wave split) ----------------
__global__ __launch_bounds__(256, 3)
void flash_k(const u16* __restrict__ qbf, const u16* __restrict__ kbf, const u16* __restrict__ vt,
             const int* __restrict__ seq_lens, u16* __restrict__ attnb)
{
  __shared__ char smem[49152];  // [0,16K) K | [16K,32K) V^T ; epi: [0,32K) O1-exchange, [32K,48K) ml+Os
  const int t = threadIdx.x;
  const int lane = t & 63;
  const int h = lane >> 5;          // half-wave
  const int l31 = lane & 31;
  const int wq = (t >> 6) & 1;
  const int wk = t >> 7;

  // XCD swizzle: 32 q-tiles of one (head,batch) pair on one XCD; 3 pairs/XCD
  const int u  = blockIdx.x;              // 0..767
  const int qt = (u >> 3) & 31;
  const int pr = (u & 7) + 8 * (u >> 8);  // 0..23
  const int hh = pr % 12;
  const int b  = pr / 12;

  const int q0 = qt * 64 + wq * 32;
  const int tokbase = b * SEQ;
  const int kvlen = min(seq_lens[b], SEQ);
  const int ntiles = (kvlen + 63) >> 6;

  // Q fragments in registers (B-operand layout: n=l31 -> query, k=h*8+j -> d)
  bfx8 qf[8];
  {
    const u16* qp = qbf + (size_t)(tokbase + q0 + l31)*DIM + hh*HD + h*8;
    #pragma unroll
    for (int c = 0; c < 8; ++c) qf[c] = *(const bfx8*)(qp + c*16);
  }

  fx16 o[4];
  #pragma unroll
  for (int dt = 0; dt < 4; ++dt)
    #pragma unroll
    for (int r = 0; r < 16; ++r) o[dt][r] = 0.f;
  float mrow = -1e30f, lrow = 0.f;

  const int kri = t >> 4, kseg = t & 15;
  const int vri = t >> 3, vseg = t & 7;
  const int krow = wk*32 + l31;

  for (int kt = 0; kt < ntiles; ++kt){
    { // stage K tile: 64 rows x 256B
      #pragma unroll
      for (int s = 0; s < 4; ++s){
        const int row = s*16 + kri;
        const int sg = kseg ^ (row & 15);
        gl_lds16(kbf + (size_t)(tokbase + kt*64 + row)*DIM + hh*HD + sg*8, smem + s*4096 + t*16);
      }
    }
    { // stage V^T tile: 128 d-rows x 128B
      #pragma unroll
      for (int s = 0; s < 4; ++s){
        const int row = s*32 + vri;
        const int sg = vseg ^ (row & 7);
        gl_lds16(vt + (size_t)((b*NH + hh)*HD + row)*SEQ + kt*64 + sg*8, smem + 16384 + s*4096 + t*16);
      }
    }
    __syncthreads();

    // S^T (32k x 32q) for this wave's key half
    fx16 st;
    #pragma unroll
    for (int r = 0; r < 16; ++r) st[r] = 0.f;
    #pragma unroll
    for (int c = 0; c < 8; ++c){
      const bfx8 kf = *(const bfx8*)(smem + krow*256 + (((2*c + h) ^ (krow & 15)) << 4));
      st = __builtin_amdgcn_mfma_f32_32x32x16_bf16(kf, qf[c], st, 0, 0, 0);
    }

    if ((kt == ntiles - 1) && (kvlen & 63)){
      #pragma unroll
      for (int r = 0; r < 16; ++r){
        const int key = kt*64 + wk*32 + (r & 3) + 8*(r >> 2) + 4*h;
        if (key >= kvlen) st[r] = -1e30f;
      }
    }

    float tm = st[0];
    #pragma unroll
    for (int r = 1; r < 16; ++r) tm = fmaxf(tm, st[r]);
    tm = fmaxf(tm, __shfl_xor(tm, 32));
    if (__any(tm > mrow)){
      const float mnew = fmaxf(mrow, tm);
      const float alpha = __expf(mrow - mnew);
      lrow *= alpha;
      #pragma unroll
      for (int dt = 0; dt < 4; ++dt)
        #pragma unroll
        for (int r = 0; r < 16; ++r) o[dt][r] *= alpha;
      mrow = mnew;
    }

    uint32_t tt[16];
    float ps = 0.f;
    #pragma unroll
    for (int r = 0; r < 16; ++r){
      union { float f; uint32_t u; } e; e.f = __expf(st[r] - mrow);
      const uint32_t uu = e.u + 0x8000u;
      tt[r] = uu;
      union { uint32_t u; float f; } pm; pm.u = uu & 0xFFFF0000u;
      ps += pm.f;
    }
    ps += __shfl_xor(ps, 32);
    lrow += ps;

    sx4 pb[4];
    #pragma unroll
    for (int ks = 0; ks < 4; ++ks){
      union { uint32_t u[2]; sx4 s; } pk;
      pk.u[0] = __builtin_amdgcn_perm(tt[4*ks+1], tt[4*ks+0], 0x07060302u);
      pk.u[1] = __builtin_amdgcn_perm(tt[4*ks+3], tt[4*ks+2], 0x07060302u);
      pb[ks] = pk.s;
    }

    #pragma unroll
    for (int ks = 0; ks < 4; ++ks){
      #pragma unroll
      for (int dt = 0; dt < 4; ++dt){
        const int row = dt*32 + l31;
        const sx4 vf = *(const sx4*)(smem + 16384 + row*128 + ((((wk<<2) + ks) ^ (row & 7)) << 4) + (h << 3));
        o[dt] = __builtin_amdgcn_mfma_f32_32x32x8bf16_1k(vf, pb[ks], o[dt], 0, 0, 0);
      }
    }
    __syncthreads();
  }

  // ---- epilogue: merge wk halves, normalize, store ----
  float* mlbuf = (float*)(smem + 32768);     // [wk][wq][2][32]
  if (h == 0){
    mlbuf[((wk*2 + wq)*2 + 0)*32 + l31] = mrow;
    mlbuf[((wk*2 + wq)*2 + 1)*32 + l31] = lrow;
  }
  __syncthreads();
  const float mo = mlbuf[(((wk^1)*2 + wq)*2 + 0)*32 + l31];
  const float lo = mlbuf[(((wk^1)*2 + wq)*2 + 1)*32 + l31];
  const float M  = fmaxf(mrow, mo);
  const float f  = __expf(mrow - M);
  const float L  = lrow * f + lo * __expf(mo - M);
  #pragma unroll
  for (int dt = 0; dt < 4; ++dt)
    #pragma unroll
    for (int r = 0; r < 16; ++r) o[dt][r] *= f;
  __syncthreads();

  float* xbuf = (float*)smem;                 // [wq][32 q][128 d] fp32 (wk=1's scaled O)
  if (wk == 1){
    #pragma unroll
    for (int dt = 0; dt < 4; ++dt)
      #pragma unroll
      for (int rq = 0; rq < 4; ++rq){
        const int d = dt*32 + 8*rq + 4*h;
        fx4 v4; v4[0]=o[dt][4*rq]; v4[1]=o[dt][4*rq+1]; v4[2]=o[dt][4*rq+2]; v4[3]=o[dt][4*rq+3];
        *(fx4*)(xbuf + (size_t)(wq*32 + l31)*128 + d) = v4;
      }
  }
  __syncthreads();

  u16* Os = (u16*)(smem + 32768);             // [64 q][128 d] bf16
  if (wk == 0){
    const float invL = 1.0f / L;
    #pragma unroll
    for (int dt = 0; dt < 4; ++dt)
      #pragma unroll
      for (int rq = 0; rq < 4; ++rq){
        const int d = dt*32 + 8*rq + 4*h;
        const fx4 p4 = *(const fx4*)(xbuf + (size_t)(wq*32 + l31)*128 + d);
        ux4 b4;
        #pragma unroll
        for (int j = 0; j < 4; ++j) b4[j] = f2bf((o[dt][4*rq + j] + p4[j]) * invL);
        *(ux4*)(Os + (size_t)(wq*32 + l31)*128 + d) = b4;
      }
  }
  __syncthreads();
  {
    const int ri = t >> 4, seg = t & 15;
    #pragma unroll
    for (int s = 0; s < 4; ++s){
      const int row = s*16 + ri;
      const ux8 val = *(const ux8*)(Os + row*128 + seg*8);
      *(ux8*)(attnb + (size_t)(tokbase + qt*64 + row)*DIM + hh*HD + seg*8) = val;
    }
  }
}

// ---------------- launch ----------------
extern "C" void kernel_launch(void* const* d_in, const int* in_sizes, int n_in,
                              void* d_out, int out_size, void* d_ws, size_t ws_size,
                              hipStream_t stream)
{
  (void)in_sizes; (void)n_in; (void)out_size; (void)ws_size;
  const float* x      = (const float*)d_in[0];
  const float* wq     = (const float*)d_in[1];
  const float* bq     = (const float*)d_in[2];
  const float* wk     = (const float*)d_in[3];
  const float* bk     = (const float*)d_in[4];
  const float* wv     = (const float*)d_in[5];
  const float* bv     = (const float*)d_in[6];
  const float* wo     = (const float*)d_in[7];
  const float* bo     = (const float*)d_in[8];
  const float* gq     = (const float*)d_in[9];
  const float* gk     = (const float*)d_in[10];
  const float* freqs  = (const float*)d_in[11];
  const int*   seqls  = (const int*)d_in[12];

  char* ws = (char*)d_ws;
  u16* xb   = (u16*)(ws + 0);
  u16* wqb  = (u16*)(ws + 12582912);
  u16* wkb  = (u16*)(ws + 17301504);
  u16* wvb  = (u16*)(ws + 22020096);
  u16* wob  = (u16*)(ws + 26738688);
  u16* qraw = (u16*)(ws + 31457280);   // reused as attnb after normrope
  u16* kraw = (u16*)(ws + 44040192);
  u16* vt   = (u16*)(ws + 56623104);   // V directly in [b,h,d,tok] from gemm epilogue
  u16* qbf  = (u16*)(ws + 69206016);
  u16* kbf  = (u16*)(ws + 81788928);
  float* ssq = (float*)(ws + 94371840);
  float* ssk = (float*)(ws + 94388224);
  u16* attnb = qraw;

  (void)hipMemsetAsync(ssq, 0, 32768, stream);   // zero both sumsq buffers (contiguous)

  convert_k   <<<15360, 256, 0, stream>>>(x, wq, wk, wv, wo, xb, wqb, wkb, wvb, wob);
  gemm_qkv_k  <<<dim3(12, 32, 3), 256, 0, stream>>>(xb, wqb, wkb, wvb, bq, bk, bv,
                                                    qraw, kraw, vt, ssq, ssk);
  normrope_k  <<<dim3(4096, 2), 256, 0, stream>>>(qraw, kraw, ssq, ssk, gq, gk, freqs, qbf, kbf);
  flash_k     <<<dim3(768), 256, 0, stream>>>(qbf, kbf, vt, seqls, attnb);
  gemm_out_k  <<<dim3(12, 32), 256, 0, stream>>>(attnb, wob, bo, (float*)d_out);
}